// Round 4
// baseline (296.623 us; speedup 1.0000x reference)
//
#include <hip/hip_runtime.h>
#include <hip/hip_bf16.h>
#include <cstdint>

#define BB   2
#define SS   1024
#define HIDD 768
#define NH   12
#define DH   64
#define BH   (BB*NH)   // 24

typedef short bf16x8 __attribute__((ext_vector_type(8)));
typedef float f32x4  __attribute__((ext_vector_type(4)));

__device__ __forceinline__ unsigned short f2b(float x) {
    union { float f; uint32_t u; } v; v.f = x;
    uint32_t u = v.u;
    uint32_t r = (u + 0x7fffu + ((u >> 16) & 1u)) >> 16;
    return (unsigned short)r;
}

__device__ __forceinline__ void async16(const void* g, void* l) {
    __builtin_amdgcn_global_load_lds(
        (const __attribute__((address_space(1))) unsigned int*)g,
        (__attribute__((address_space(3))) unsigned int*)l,
        16, 0, 0);
}

// ---------------- kernel 1: hidden_states fp32 -> bf16 ----------------
__global__ void cvt_x(const float* __restrict__ x, unsigned short* __restrict__ xb) {
    int i = blockIdx.x * blockDim.x + threadIdx.x;   // one float4 per thread
    float4 v = ((const float4*)x)[i];
    ushort4 o;
    o.x = f2b(v.x); o.y = f2b(v.y); o.z = f2b(v.z); o.w = f2b(v.w);
    ((ushort4*)xb)[i] = o;
}

// ------------- kernel 2: W [k][n] fp32 -> Wt [n][k] bf16 (q|k|v) -------------
__global__ void transpose_w(const float* __restrict__ Wq, const float* __restrict__ Wk,
                            const float* __restrict__ Wv, unsigned short* __restrict__ Wt) {
    __shared__ float tile[32][33];
    const int w = blockIdx.z;
    const float* W = (w == 0) ? Wq : (w == 1) ? Wk : Wv;
    const int tx = threadIdx.x & 31, ty = threadIdx.x >> 5;   // 32 x 8
    const int k0 = blockIdx.x * 32, n0 = blockIdx.y * 32;
    for (int p = 0; p < 4; ++p)
        tile[ty + p * 8][tx] = W[(k0 + ty + p * 8) * HIDD + n0 + tx];
    __syncthreads();
    for (int p = 0; p < 4; ++p) {
        int n = n0 + ty + p * 8;
        Wt[(w * HIDD + n) * HIDD + k0 + tx] = f2b(tile[tx][ty + p * 8]);
    }
}

// ------------- kernel 3: QKV GEMM 2048x2304x768, bf16 MFMA -------------
// 128x64 tiles (576 blocks), BK=32, double-buffered LDS with post-barrier
// load issue so the barrier vmcnt drain overlaps compute.
__global__ __launch_bounds__(256) void qkv_gemm(
    const unsigned short* __restrict__ Xb, const unsigned short* __restrict__ Wt,
    const float* __restrict__ bq, const float* __restrict__ bk, const float* __restrict__ bv,
    unsigned short* __restrict__ Qh, unsigned short* __restrict__ Kh,
    unsigned short* __restrict__ Vh) {
    __shared__ __align__(16) unsigned short lA[2][128 * 32];
    __shared__ __align__(16) unsigned short lB[2][64 * 32];
    const int t = threadIdx.x;
    const int wave = t >> 6, lane = t & 63;
    const int l15 = lane & 15, quad = lane >> 4;
    const int m0 = blockIdx.x * 128;
    const int n0 = blockIdx.y * 64;
    const int wm = wave * 32;          // wave owns 32 rows x 64 cols

    f32x4 acc[2][4] = {};

    // stage k-chunk into buffer b
    auto stage = [&](int k0, int b) {
        // A: 128x32 = 512 chunks of 16B, 2 per thread
        #pragma unroll
        for (int r = 0; r < 2; ++r) {
            int ci = r * 256 + t;
            async16(Xb + (m0 + (ci >> 2)) * HIDD + k0 + (ci & 3) * 8,
                    &lA[b][(r * 256 + wave * 64) * 8]);
        }
        // B: 64x32 = 256 chunks, 1 per thread
        async16(Wt + (n0 + (t >> 2)) * HIDD + k0 + (t & 3) * 8,
                &lB[b][(wave * 64) * 8]);
    };

    stage(0, 0);
    for (int ki = 0; ki < 24; ++ki) {
        const int cur = ki & 1;
        __syncthreads();                 // drains stage(ki); protects buffer reuse
        if (ki < 23) stage((ki + 1) * 32, cur ^ 1);   // in flight during compute
        bf16x8 af[2], bf[4];
        #pragma unroll
        for (int i = 0; i < 2; ++i)
            af[i] = *(const bf16x8*)&lA[cur][(wm + i * 16 + l15) * 32 + quad * 8];
        #pragma unroll
        for (int j = 0; j < 4; ++j)
            bf[j] = *(const bf16x8*)&lB[cur][(j * 16 + l15) * 32 + quad * 8];
        #pragma unroll
        for (int i = 0; i < 2; ++i)
            #pragma unroll
            for (int j = 0; j < 4; ++j)
                acc[i][j] = __builtin_amdgcn_mfma_f32_16x16x32_bf16(af[i], bf[j], acc[i][j], 0, 0, 0);
    }

    const int sect = (n0 >= 1536) ? 2 : (n0 >= 768) ? 1 : 0;   // uniform per block
    const float* bias = (sect == 0) ? bq : (sect == 1) ? bk : bv;
    unsigned short* dst = (sect == 0) ? Qh : (sect == 1) ? Kh : Vh;
    const float scale = (sect == 0) ? 0.125f : 1.0f;
    #pragma unroll
    for (int i = 0; i < 2; ++i) {
        #pragma unroll
        for (int j = 0; j < 4; ++j) {
            int n  = n0 + j * 16 + l15;
            int nn = n - sect * HIDD;
            int h = nn >> 6, d = nn & 63;
            float bval = bias[nn];
            #pragma unroll
            for (int r = 0; r < 4; ++r) {
                int m = m0 + wm + i * 16 + quad * 4 + r;   // C layout: row=quad*4+reg
                int b = m >> 10, s = m & 1023;
                float v = (acc[i][j][r] + bval) * scale;
                dst[((size_t)(b * NH + h) * SS + s) * DH + d] = f2b(v);
            }
        }
    }
}

// ------------- kernel 3b: Vh [bh][s][d] -> VhT [bh][d][s] -------------
__global__ __launch_bounds__(256) void transpose_v(
    const unsigned short* __restrict__ Vh, unsigned short* __restrict__ VhT) {
    __shared__ unsigned short tile[64][65];
    const int t = threadIdx.x;
    const int bh = blockIdx.y;
    const int s0 = blockIdx.x * 64;
    const int tx = t & 63, ty = t >> 6;   // 64 x 4
    const unsigned short* src = Vh + (size_t)bh * SS * DH;
    #pragma unroll
    for (int p = 0; p < 16; ++p)
        tile[ty + p * 4][tx] = src[(size_t)(s0 + ty + p * 4) * DH + tx];
    __syncthreads();
    unsigned short* dst = VhT + (size_t)bh * DH * SS;
    #pragma unroll
    for (int p = 0; p < 16; ++p)
        dst[(size_t)(ty + p * 4) * SS + s0 + tx] = tile[tx][ty + p * 4];
}

// ------------- kernel 4: flash attention with additive bias -------------
// grid: (S/16, BH). 4 waves/block; same 16 query rows, disjoint 256-key
// ranges, block combine. Register-prefetch pipeline: K+bias for tile t+1
// in flight during tile t's softmax; bias loaded directly in MFMA C-layout.
__global__ __launch_bounds__(256, 2) void flash_attn(
    const unsigned short* __restrict__ Qh, const unsigned short* __restrict__ Kh,
    const unsigned short* __restrict__ VhT,
    const float* __restrict__ rel, const float* __restrict__ rel2d,
    const float* __restrict__ amask, const float* __restrict__ hmask,
    float* __restrict__ out) {
    // union: per-wave P tiles (4*1152*2B = 9216B) alias the combine area
    __shared__ __align__(16) char smemraw[17408];
    float* o_l = (float*)smemraw;            // [4][16][64] = 16384 B
    float* m_l = (float*)(smemraw + 16384);  // 64 floats
    float* l_l = (float*)(smemraw + 16640);  // 64 floats

    const int t = threadIdx.x;
    const int wave = t >> 6, lane = t & 63;
    const int l15 = lane & 15, quad = lane >> 4;
    const int bh = blockIdx.y;
    const int b = bh / NH, h = bh % NH;
    const int m0 = blockIdx.x * 16;                 // 16 query rows, shared by waves

    const unsigned short* Qp = Qh + (size_t)bh * SS * DH;
    const unsigned short* Kp = Kh + (size_t)bh * SS * DH;
    const unsigned short* Vp = VhT + (size_t)bh * DH * SS;
    const float* relp  = rel   + (size_t)bh * SS * SS;
    const float* rel2p = rel2d + (size_t)bh * SS * SS;
    const float* maskp = amask + (size_t)b * SS;

    unsigned short* Pw = (unsigned short*)smemraw + wave * (16 * 72);

    const int jbeg = wave * 256;

    bf16x8 qf0 = *(const bf16x8*)&Qp[(m0 + l15) * DH + quad * 8];
    bf16x8 qf1 = *(const bf16x8*)&Qp[(m0 + l15) * DH + 32 + quad * 8];

    // attention-mask values for this wave's 256 cols, C-layout (col=tile*64+c*16+l15)
    float mk_all[16];
    #pragma unroll
    for (int tc = 0; tc < 16; ++tc)
        mk_all[tc] = maskp[jbeg + (tc >> 2) * 64 + (tc & 3) * 16 + l15];

    f32x4 o[4] = {};
    float mrow[4] = {-1e30f, -1e30f, -1e30f, -1e30f};
    float lrow[4] = {0.f, 0.f, 0.f, 0.f};

    // prefetch state: bias (C-layout scalar) + K fragments for the NEXT tile
    float ra[16], rb[16];
    bf16x8 k0f[4], k1f[4];

    #define LOAD_BIAS(J0)                                                      \
        _Pragma("unroll")                                                      \
        for (int c = 0; c < 4; ++c)                                            \
            _Pragma("unroll")                                                  \
            for (int r = 0; r < 4; ++r) {                                      \
                size_t idx = (size_t)(m0 + quad * 4 + r) * SS + (J0) + c * 16 + l15; \
                ra[c * 4 + r] = relp[idx];                                     \
                rb[c * 4 + r] = rel2p[idx];                                    \
            }
    #define LOAD_K(J0)                                                         \
        _Pragma("unroll")                                                      \
        for (int c = 0; c < 4; ++c) {                                          \
            k0f[c] = *(const bf16x8*)&Kp[((J0) + c * 16 + l15) * DH + quad * 8];      \
            k1f[c] = *(const bf16x8*)&Kp[((J0) + c * 16 + l15) * DH + 32 + quad * 8]; \
        }

    LOAD_BIAS(jbeg)
    LOAD_K(jbeg)

    #pragma unroll
    for (int tt = 0; tt < 4; ++tt) {
        const int j0 = jbeg + tt * 64;
        // ---- issue V loads now; consumed after softmax (~1500 cy later) ----
        bf16x8 v0f[4], v1f[4];
        #pragma unroll
        for (int dt = 0; dt < 4; ++dt) {
            v0f[dt] = *(const bf16x8*)&Vp[(dt * 16 + l15) * SS + j0 + quad * 8];
            v1f[dt] = *(const bf16x8*)&Vp[(dt * 16 + l15) * SS + j0 + 32 + quad * 8];
        }
        // ---- scores from prefetched K ----
        f32x4 sc[4] = {};
        #pragma unroll
        for (int c = 0; c < 4; ++c) {
            sc[c] = __builtin_amdgcn_mfma_f32_16x16x32_bf16(qf0, k0f[c], sc[c], 0, 0, 0);
            sc[c] = __builtin_amdgcn_mfma_f32_16x16x32_bf16(qf1, k1f[c], sc[c], 0, 0, 0);
        }
        // ---- fused bias add from prefetched regs (already C-layout) ----
        float sv[4][4];
        #pragma unroll
        for (int c = 0; c < 4; ++c)
            #pragma unroll
            for (int r = 0; r < 4; ++r)
                sv[c][r] = sc[c][r] + (ra[c * 4 + r] + rb[c * 4 + r]) * 0.125f
                         + mk_all[tt * 4 + c];
        // ---- prefetch NEXT tile's bias + K (in flight during softmax) ----
        if (tt < 3) {
            LOAD_BIAS(j0 + 64)
            LOAD_K(j0 + 64)
        }
        // ---- online softmax per row (reg r <-> row quad*4+r) ----
        float alpha[4];
        #pragma unroll
        for (int r = 0; r < 4; ++r) {
            float mx = fmaxf(fmaxf(sv[0][r], sv[1][r]), fmaxf(sv[2][r], sv[3][r]));
            #pragma unroll
            for (int off = 1; off < 16; off <<= 1) mx = fmaxf(mx, __shfl_xor(mx, off, 64));
            float mnew = fmaxf(mrow[r], mx);
            alpha[r] = __expf(mrow[r] - mnew);
            mrow[r] = mnew;
            float rs = 0.f;
            #pragma unroll
            for (int c = 0; c < 4; ++c) {
                float p = __expf(sv[c][r] - mnew);
                sv[c][r] = p;
                rs += p;
            }
            #pragma unroll
            for (int off = 1; off < 16; off <<= 1) rs += __shfl_xor(rs, off, 64);
            lrow[r] = lrow[r] * alpha[r] + rs;
            o[0][r] *= alpha[r]; o[1][r] *= alpha[r]; o[2][r] *= alpha[r]; o[3][r] *= alpha[r];
        }
        // ---- P: C layout -> LDS [m][t] (A-operand layout), bf16 ----
        #pragma unroll
        for (int c = 0; c < 4; ++c)
            #pragma unroll
            for (int r = 0; r < 4; ++r)
                Pw[(quad * 4 + r) * 72 + c * 16 + l15] = f2b(sv[c][r]);

        bf16x8 pf0 = *(const bf16x8*)&Pw[l15 * 72 + quad * 8];
        bf16x8 pf1 = *(const bf16x8*)&Pw[l15 * 72 + 32 + quad * 8];
        // ---- O += P . V ----
        #pragma unroll
        for (int dt = 0; dt < 4; ++dt) {
            o[dt] = __builtin_amdgcn_mfma_f32_16x16x32_bf16(pf0, v0f[dt], o[dt], 0, 0, 0);
            o[dt] = __builtin_amdgcn_mfma_f32_16x16x32_bf16(pf1, v1f[dt], o[dt], 0, 0, 0);
        }
    }
    #undef LOAD_BIAS
    #undef LOAD_K

    // ---- block combine across the 4 key-range partials ----
    __syncthreads();   // all waves done; P area is free for combine reuse
    #pragma unroll
    for (int dt = 0; dt < 4; ++dt)
        #pragma unroll
        for (int r = 0; r < 4; ++r)
            o_l[(wave * 16 + quad * 4 + r) * 64 + dt * 16 + l15] = o[dt][r];
    if (l15 == 0) {
        #pragma unroll
        for (int r = 0; r < 4; ++r) {
            m_l[wave * 16 + quad * 4 + r] = mrow[r];
            l_l[wave * 16 + quad * 4 + r] = lrow[r];
        }
    }
    __syncthreads();

    const float hm = hmask[h];
    const int col = t & 63, rsel = t >> 6;
    #pragma unroll
    for (int rr = 0; rr < 4; ++rr) {
        int row = rsel * 4 + rr;
        float m01 = fmaxf(m_l[row], m_l[16 + row]);
        float m23 = fmaxf(m_l[32 + row], m_l[48 + row]);
        float mt = fmaxf(m01, m23);
        float lt = 0.f, val = 0.f;
        #pragma unroll
        for (int w = 0; w < 4; ++w) {
            float sc = __expf(m_l[w * 16 + row] - mt);
            lt += sc * l_l[w * 16 + row];
            val += sc * o_l[(w * 16 + row) * 64 + col];
        }
        int s = m0 + row;
        out[((size_t)(b * SS + s)) * HIDD + h * DH + col] = val * hm / lt;
    }
}

extern "C" void kernel_launch(void* const* d_in, const int* in_sizes, int n_in,
                              void* d_out, int out_size, void* d_ws, size_t ws_size,
                              hipStream_t stream) {
    const float* hs    = (const float*)d_in[0];
    const float* am    = (const float*)d_in[1];
    const float* hm    = (const float*)d_in[2];
    const float* rel   = (const float*)d_in[3];
    const float* rel2d = (const float*)d_in[4];
    const float* Wq    = (const float*)d_in[5];
    const float* bq    = (const float*)d_in[6];
    const float* Wk    = (const float*)d_in[7];
    const float* bk    = (const float*)d_in[8];
    const float* Wv    = (const float*)d_in[9];
    const float* bv    = (const float*)d_in[10];
    float* out = (float*)d_out;

    unsigned short* Xb  = (unsigned short*)d_ws;              // 2048*768
    unsigned short* Wt  = Xb + 2048 * HIDD;                   // 3*768*768
    unsigned short* Qh  = Wt + 3 * HIDD * HIDD;               // 24*1024*64 each
    unsigned short* Kh  = Qh + (size_t)BH * SS * DH;
    unsigned short* Vh  = Kh + (size_t)BH * SS * DH;
    unsigned short* VhT = Vh + (size_t)BH * SS * DH;

    cvt_x<<<(2048 * HIDD / 4) / 256, 256, 0, stream>>>(hs, Xb);
    dim3 gT(24, 24, 3);
    transpose_w<<<gT, 256, 0, stream>>>(Wq, Wk, Wv, Wt);
    dim3 gG(16, 36);
    qkv_gemm<<<gG, 256, 0, stream>>>(Xb, Wt, bq, bk, bv, Qh, Kh, Vh);
    dim3 gV(16, BH);
    transpose_v<<<gV, 256, 0, stream>>>(Vh, VhT);
    dim3 gF(64, BH);
    flash_attn<<<gF, 256, 0, stream>>>(Qh, Kh, VhT, rel, rel2d, am, hm, out);
}

// Round 5
// 291.895 us; speedup vs baseline: 1.0162x; 1.0162x over previous
//
#include <hip/hip_runtime.h>
#include <hip/hip_bf16.h>
#include <cstdint>

#define BB   2
#define SS   1024
#define HIDD 768
#define NH   12
#define DH   64
#define BH   (BB*NH)   // 24

typedef short bf16x8 __attribute__((ext_vector_type(8)));
typedef float f32x4  __attribute__((ext_vector_type(4)));

__device__ __forceinline__ unsigned short f2b(float x) {
    union { float f; uint32_t u; } v; v.f = x;
    uint32_t u = v.u;
    uint32_t r = (u + 0x7fffu + ((u >> 16) & 1u)) >> 16;
    return (unsigned short)r;
}

__device__ __forceinline__ void async16(const void* g, void* l) {
    __builtin_amdgcn_global_load_lds(
        (const __attribute__((address_space(1))) unsigned int*)g,
        (__attribute__((address_space(3))) unsigned int*)l,
        16, 0, 0);
}

// ---------------- kernel 1: hidden_states fp32 -> bf16 ----------------
__global__ void cvt_x(const float* __restrict__ x, unsigned short* __restrict__ xb) {
    int i = blockIdx.x * blockDim.x + threadIdx.x;   // one float4 per thread
    float4 v = ((const float4*)x)[i];
    ushort4 o;
    o.x = f2b(v.x); o.y = f2b(v.y); o.z = f2b(v.z); o.w = f2b(v.w);
    ((ushort4*)xb)[i] = o;
}

// ------------- kernel 2: W [k][n] fp32 -> Wt [n][k] bf16 (q|k|v) -------------
__global__ void transpose_w(const float* __restrict__ Wq, const float* __restrict__ Wk,
                            const float* __restrict__ Wv, unsigned short* __restrict__ Wt) {
    __shared__ float tile[32][33];
    const int w = blockIdx.z;
    const float* W = (w == 0) ? Wq : (w == 1) ? Wk : Wv;
    const int tx = threadIdx.x & 31, ty = threadIdx.x >> 5;   // 32 x 8
    const int k0 = blockIdx.x * 32, n0 = blockIdx.y * 32;
    for (int p = 0; p < 4; ++p)
        tile[ty + p * 8][tx] = W[(k0 + ty + p * 8) * HIDD + n0 + tx];
    __syncthreads();
    for (int p = 0; p < 4; ++p) {
        int n = n0 + ty + p * 8;
        Wt[(w * HIDD + n) * HIDD + k0 + tx] = f2b(tile[tx][ty + p * 8]);
    }
}

// ------------- kernel 3: QKV GEMM 2048x2304x768, bf16 MFMA -------------
// 128x64 tiles (576 blocks), BK=32, double-buffered LDS with post-barrier
// load issue so the barrier vmcnt drain overlaps compute.
__global__ __launch_bounds__(256) void qkv_gemm(
    const unsigned short* __restrict__ Xb, const unsigned short* __restrict__ Wt,
    const float* __restrict__ bq, const float* __restrict__ bk, const float* __restrict__ bv,
    unsigned short* __restrict__ Qh, unsigned short* __restrict__ Kh,
    unsigned short* __restrict__ Vh) {
    __shared__ __align__(16) unsigned short lA[2][128 * 32];
    __shared__ __align__(16) unsigned short lB[2][64 * 32];
    const int t = threadIdx.x;
    const int wave = t >> 6, lane = t & 63;
    const int l15 = lane & 15, quad = lane >> 4;
    const int m0 = blockIdx.x * 128;
    const int n0 = blockIdx.y * 64;
    const int wm = wave * 32;          // wave owns 32 rows x 64 cols

    f32x4 acc[2][4] = {};

    // stage k-chunk into buffer b
    auto stage = [&](int k0, int b) {
        // A: 128x32 = 512 chunks of 16B, 2 per thread
        #pragma unroll
        for (int r = 0; r < 2; ++r) {
            int ci = r * 256 + t;
            async16(Xb + (m0 + (ci >> 2)) * HIDD + k0 + (ci & 3) * 8,
                    &lA[b][(r * 256 + wave * 64) * 8]);
        }
        // B: 64x32 = 256 chunks, 1 per thread
        async16(Wt + (n0 + (t >> 2)) * HIDD + k0 + (t & 3) * 8,
                &lB[b][(wave * 64) * 8]);
    };

    stage(0, 0);
    for (int ki = 0; ki < 24; ++ki) {
        const int cur = ki & 1;
        __syncthreads();                 // drains stage(ki); protects buffer reuse
        if (ki < 23) stage((ki + 1) * 32, cur ^ 1);   // in flight during compute
        bf16x8 af[2], bf[4];
        #pragma unroll
        for (int i = 0; i < 2; ++i)
            af[i] = *(const bf16x8*)&lA[cur][(wm + i * 16 + l15) * 32 + quad * 8];
        #pragma unroll
        for (int j = 0; j < 4; ++j)
            bf[j] = *(const bf16x8*)&lB[cur][(j * 16 + l15) * 32 + quad * 8];
        #pragma unroll
        for (int i = 0; i < 2; ++i)
            #pragma unroll
            for (int j = 0; j < 4; ++j)
                acc[i][j] = __builtin_amdgcn_mfma_f32_16x16x32_bf16(af[i], bf[j], acc[i][j], 0, 0, 0);
    }

    const int sect = (n0 >= 1536) ? 2 : (n0 >= 768) ? 1 : 0;   // uniform per block
    const float* bias = (sect == 0) ? bq : (sect == 1) ? bk : bv;
    unsigned short* dst = (sect == 0) ? Qh : (sect == 1) ? Kh : Vh;
    const float scale = (sect == 0) ? 0.125f : 1.0f;
    #pragma unroll
    for (int i = 0; i < 2; ++i) {
        #pragma unroll
        for (int j = 0; j < 4; ++j) {
            int n  = n0 + j * 16 + l15;
            int nn = n - sect * HIDD;
            int h = nn >> 6, d = nn & 63;
            float bval = bias[nn];
            #pragma unroll
            for (int r = 0; r < 4; ++r) {
                int m = m0 + wm + i * 16 + quad * 4 + r;   // C layout: row=quad*4+reg
                int b = m >> 10, s = m & 1023;
                float v = (acc[i][j][r] + bval) * scale;
                dst[((size_t)(b * NH + h) * SS + s) * DH + d] = f2b(v);
            }
        }
    }
}

// ------------- kernel 3b: Vh [bh][s][d] -> VhT [bh][d][s] -------------
__global__ __launch_bounds__(256) void transpose_v(
    const unsigned short* __restrict__ Vh, unsigned short* __restrict__ VhT) {
    __shared__ unsigned short tile[64][65];
    const int t = threadIdx.x;
    const int bh = blockIdx.y;
    const int s0 = blockIdx.x * 64;
    const int tx = t & 63, ty = t >> 6;   // 64 x 4
    const unsigned short* src = Vh + (size_t)bh * SS * DH;
    #pragma unroll
    for (int p = 0; p < 16; ++p)
        tile[ty + p * 4][tx] = src[(size_t)(s0 + ty + p * 4) * DH + tx];
    __syncthreads();
    unsigned short* dst = VhT + (size_t)bh * DH * SS;
    #pragma unroll
    for (int p = 0; p < 16; ++p)
        dst[(size_t)(ty + p * 4) * SS + s0 + tx] = tile[tx][ty + p * 4];
}

// ------------- kernel 4: flash attention with additive bias -------------
// grid: (S/16, BH). 4 waves/block; same 16 query rows, disjoint 256-key
// ranges, block combine. Per tile: ALL loads (bias via global_load_lds into
// wave-private LDS, K+V into regs) issued back-to-back, then ONE vmcnt(0)
// drain (asm volatile, cannot be reordered). One memory round per tile.
__global__ __launch_bounds__(256, 3) void flash_attn(
    const unsigned short* __restrict__ Qh, const unsigned short* __restrict__ Kh,
    const unsigned short* __restrict__ VhT,
    const float* __restrict__ rel, const float* __restrict__ rel2d,
    const float* __restrict__ amask, const float* __restrict__ hmask,
    float* __restrict__ out) {
    // layout: [0,32768) bias staging (4 waves x 2 arrays x 16x64 fl)
    //         [32768,41984) P tiles (4 waves x 16x72 bf16)
    // combine phase aliases [0,16896): o_l 16384 + m_l 256 + l_l 256
    __shared__ __align__(16) char smemraw[41984];

    const int t = threadIdx.x;
    const int wave = t >> 6, lane = t & 63;
    const int l15 = lane & 15, quad = lane >> 4;
    const int bh = blockIdx.y;
    const int b = bh / NH, h = bh % NH;
    const int m0 = blockIdx.x * 16;                 // 16 query rows, shared by waves

    const unsigned short* Qp = Qh + (size_t)bh * SS * DH;
    const unsigned short* Kp = Kh + (size_t)bh * SS * DH;
    const unsigned short* Vp = VhT + (size_t)bh * DH * SS;
    const float* relp  = rel   + (size_t)bh * SS * SS;
    const float* rel2p = rel2d + (size_t)bh * SS * SS;
    const float* maskp = amask + (size_t)b * SS;

    float* stgA = (float*)(smemraw + wave * 8192);          // 16x64 rel
    float* stgB = stgA + 1024;                               // 16x64 rel2d
    unsigned short* Pw = (unsigned short*)(smemraw + 32768) + wave * (16 * 72);

    const int jbeg = wave * 256;

    bf16x8 qf0 = *(const bf16x8*)&Qp[(m0 + l15) * DH + quad * 8];
    bf16x8 qf1 = *(const bf16x8*)&Qp[(m0 + l15) * DH + 32 + quad * 8];

    // attention-mask values, C-layout (col = tile*64 + c*16 + l15)
    float mk_all[16];
    #pragma unroll
    for (int tc = 0; tc < 16; ++tc)
        mk_all[tc] = maskp[jbeg + (tc >> 2) * 64 + (tc & 3) * 16 + l15];

    f32x4 o[4] = {};
    float mrow[4] = {-1e30f, -1e30f, -1e30f, -1e30f};
    float lrow[4] = {0.f, 0.f, 0.f, 0.f};

    for (int tt = 0; tt < 4; ++tt) {
        const int j0 = jbeg + tt * 64;

        // ---- issue ALL of this tile's loads back-to-back ----
        // bias -> LDS (8 async16: 4 per array; instr i covers rows 4i..4i+3)
        #pragma unroll
        for (int i = 0; i < 4; ++i) {
            const float* gA = relp  + (size_t)(m0 + 4 * i + quad) * SS + j0 + l15 * 4;
            const float* gB = rel2p + (size_t)(m0 + 4 * i + quad) * SS + j0 + l15 * 4;
            async16(gA, stgA + i * 256);   // dest + lane*16B -> row-major 16x64
            async16(gB, stgB + i * 256);
        }
        // K -> regs
        bf16x8 k0f[4], k1f[4];
        #pragma unroll
        for (int c = 0; c < 4; ++c) {
            k0f[c] = *(const bf16x8*)&Kp[(j0 + c * 16 + l15) * DH + quad * 8];
            k1f[c] = *(const bf16x8*)&Kp[(j0 + c * 16 + l15) * DH + 32 + quad * 8];
        }
        // V -> regs
        bf16x8 v0f[4], v1f[4];
        #pragma unroll
        for (int dt = 0; dt < 4; ++dt) {
            v0f[dt] = *(const bf16x8*)&Vp[(dt * 16 + l15) * SS + j0 + quad * 8];
            v1f[dt] = *(const bf16x8*)&Vp[(dt * 16 + l15) * SS + j0 + 32 + quad * 8];
        }

        // ---- scores (compiler waits K as needed) ----
        f32x4 sc[4] = {};
        #pragma unroll
        for (int c = 0; c < 4; ++c) {
            sc[c] = __builtin_amdgcn_mfma_f32_16x16x32_bf16(qf0, k0f[c], sc[c], 0, 0, 0);
            sc[c] = __builtin_amdgcn_mfma_f32_16x16x32_bf16(qf1, k1f[c], sc[c], 0, 0, 0);
        }

        // ---- single drain: bias in LDS, V in regs, all landed ----
        asm volatile("s_waitcnt vmcnt(0)" ::: "memory");

        // ---- bias add in C layout (4-way LDS bank conflicts, ~free-ish) ----
        float sv[4][4];
        #pragma unroll
        for (int c = 0; c < 4; ++c)
            #pragma unroll
            for (int r = 0; r < 4; ++r) {
                int fi = (quad * 4 + r) * 64 + c * 16 + l15;
                sv[c][r] = sc[c][r] + (stgA[fi] + stgB[fi]) * 0.125f + mk_all[tt * 4 + c];
            }

        // ---- online softmax per row (reg r <-> row quad*4+r) ----
        float alpha[4];
        #pragma unroll
        for (int r = 0; r < 4; ++r) {
            float mx = fmaxf(fmaxf(sv[0][r], sv[1][r]), fmaxf(sv[2][r], sv[3][r]));
            #pragma unroll
            for (int off = 1; off < 16; off <<= 1) mx = fmaxf(mx, __shfl_xor(mx, off, 64));
            float mnew = fmaxf(mrow[r], mx);
            alpha[r] = __expf(mrow[r] - mnew);
            mrow[r] = mnew;
            float rs = 0.f;
            #pragma unroll
            for (int c = 0; c < 4; ++c) {
                float p = __expf(sv[c][r] - mnew);
                sv[c][r] = p;
                rs += p;
            }
            #pragma unroll
            for (int off = 1; off < 16; off <<= 1) rs += __shfl_xor(rs, off, 64);
            lrow[r] = lrow[r] * alpha[r] + rs;
            o[0][r] *= alpha[r]; o[1][r] *= alpha[r]; o[2][r] *= alpha[r]; o[3][r] *= alpha[r];
        }
        // ---- P: C layout -> LDS [m][t] (A-operand layout), bf16 ----
        #pragma unroll
        for (int c = 0; c < 4; ++c)
            #pragma unroll
            for (int r = 0; r < 4; ++r)
                Pw[(quad * 4 + r) * 72 + c * 16 + l15] = f2b(sv[c][r]);

        bf16x8 pf0 = *(const bf16x8*)&Pw[l15 * 72 + quad * 8];
        bf16x8 pf1 = *(const bf16x8*)&Pw[l15 * 72 + 32 + quad * 8];
        // ---- O += P . V (V already in regs) ----
        #pragma unroll
        for (int dt = 0; dt < 4; ++dt) {
            o[dt] = __builtin_amdgcn_mfma_f32_16x16x32_bf16(pf0, v0f[dt], o[dt], 0, 0, 0);
            o[dt] = __builtin_amdgcn_mfma_f32_16x16x32_bf16(pf1, v1f[dt], o[dt], 0, 0, 0);
        }
    }

    // ---- block combine across the 4 key-range partials ----
    __syncthreads();   // all waves done; staging area is free for combine reuse
    float* o_l = (float*)smemraw;            // [4][16][64]
    float* m_l = (float*)(smemraw + 16384);  // 64 floats
    float* l_l = (float*)(smemraw + 16640);  // 64 floats
    #pragma unroll
    for (int dt = 0; dt < 4; ++dt)
        #pragma unroll
        for (int r = 0; r < 4; ++r)
            o_l[(wave * 16 + quad * 4 + r) * 64 + dt * 16 + l15] = o[dt][r];
    if (l15 == 0) {
        #pragma unroll
        for (int r = 0; r < 4; ++r) {
            m_l[wave * 16 + quad * 4 + r] = mrow[r];
            l_l[wave * 16 + quad * 4 + r] = lrow[r];
        }
    }
    __syncthreads();

    const float hm = hmask[h];
    const int col = t & 63, rsel = t >> 6;
    #pragma unroll
    for (int rr = 0; rr < 4; ++rr) {
        int row = rsel * 4 + rr;
        float m01 = fmaxf(m_l[row], m_l[16 + row]);
        float m23 = fmaxf(m_l[32 + row], m_l[48 + row]);
        float mt = fmaxf(m01, m23);
        float lt = 0.f, val = 0.f;
        #pragma unroll
        for (int w = 0; w < 4; ++w) {
            float sc = __expf(m_l[w * 16 + row] - mt);
            lt += sc * l_l[w * 16 + row];
            val += sc * o_l[(w * 16 + row) * 64 + col];
        }
        int s = m0 + row;
        out[((size_t)(b * SS + s)) * HIDD + h * DH + col] = val * hm / lt;
    }
}

extern "C" void kernel_launch(void* const* d_in, const int* in_sizes, int n_in,
                              void* d_out, int out_size, void* d_ws, size_t ws_size,
                              hipStream_t stream) {
    const float* hs    = (const float*)d_in[0];
    const float* am    = (const float*)d_in[1];
    const float* hm    = (const float*)d_in[2];
    const float* rel   = (const float*)d_in[3];
    const float* rel2d = (const float*)d_in[4];
    const float* Wq    = (const float*)d_in[5];
    const float* bq    = (const float*)d_in[6];
    const float* Wk    = (const float*)d_in[7];
    const float* bk    = (const float*)d_in[8];
    const float* Wv    = (const float*)d_in[9];
    const float* bv    = (const float*)d_in[10];
    float* out = (float*)d_out;

    unsigned short* Xb  = (unsigned short*)d_ws;              // 2048*768
    unsigned short* Wt  = Xb + 2048 * HIDD;                   // 3*768*768
    unsigned short* Qh  = Wt + 3 * HIDD * HIDD;               // 24*1024*64 each
    unsigned short* Kh  = Qh + (size_t)BH * SS * DH;
    unsigned short* Vh  = Kh + (size_t)BH * SS * DH;
    unsigned short* VhT = Vh + (size_t)BH * SS * DH;

    cvt_x<<<(2048 * HIDD / 4) / 256, 256, 0, stream>>>(hs, Xb);
    dim3 gT(24, 24, 3);
    transpose_w<<<gT, 256, 0, stream>>>(Wq, Wk, Wv, Wt);
    dim3 gG(16, 36);
    qkv_gemm<<<gG, 256, 0, stream>>>(Xb, Wt, bq, bk, bv, Qh, Kh, Vh);
    dim3 gV(16, BH);
    transpose_v<<<gV, 256, 0, stream>>>(Vh, VhT);
    dim3 gF(64, BH);
    flash_attn<<<gF, 256, 0, stream>>>(Qh, Kh, VhT, rel, rel2d, am, hm, out);
}

// Round 6
// 271.771 us; speedup vs baseline: 1.0914x; 1.0740x over previous
//
#include <hip/hip_runtime.h>
#include <hip/hip_bf16.h>
#include <cstdint>

#define BB   2
#define SS   1024
#define HIDD 768
#define NH   12
#define DH   64
#define BH   (BB*NH)   // 24

typedef short bf16x8 __attribute__((ext_vector_type(8)));
typedef float f32x4  __attribute__((ext_vector_type(4)));

__device__ __forceinline__ unsigned short f2b(float x) {
    union { float f; uint32_t u; } v; v.f = x;
    uint32_t u = v.u;
    uint32_t r = (u + 0x7fffu + ((u >> 16) & 1u)) >> 16;
    return (unsigned short)r;
}

__device__ __forceinline__ void async16(const void* g, void* l) {
    __builtin_amdgcn_global_load_lds(
        (const __attribute__((address_space(1))) unsigned int*)g,
        (__attribute__((address_space(3))) unsigned int*)l,
        16, 0, 0);
}

// ---------------- kernel 1: hidden_states fp32 -> bf16 ----------------
__global__ void cvt_x(const float* __restrict__ x, unsigned short* __restrict__ xb) {
    int i = blockIdx.x * blockDim.x + threadIdx.x;   // one float4 per thread
    float4 v = ((const float4*)x)[i];
    ushort4 o;
    o.x = f2b(v.x); o.y = f2b(v.y); o.z = f2b(v.z); o.w = f2b(v.w);
    ((ushort4*)xb)[i] = o;
}

// ------------- kernel 2: W [k][n] fp32 -> Wt [n][k] bf16 (q|k|v) -------------
__global__ void transpose_w(const float* __restrict__ Wq, const float* __restrict__ Wk,
                            const float* __restrict__ Wv, unsigned short* __restrict__ Wt) {
    __shared__ float tile[32][33];
    const int w = blockIdx.z;
    const float* W = (w == 0) ? Wq : (w == 1) ? Wk : Wv;
    const int tx = threadIdx.x & 31, ty = threadIdx.x >> 5;   // 32 x 8
    const int k0 = blockIdx.x * 32, n0 = blockIdx.y * 32;
    for (int p = 0; p < 4; ++p)
        tile[ty + p * 8][tx] = W[(k0 + ty + p * 8) * HIDD + n0 + tx];
    __syncthreads();
    for (int p = 0; p < 4; ++p) {
        int n = n0 + ty + p * 8;
        Wt[(w * HIDD + n) * HIDD + k0 + tx] = f2b(tile[tx][ty + p * 8]);
    }
}

// ------------- kernel 3: QKV GEMM 2048x2304x768, bf16 MFMA -------------
__global__ __launch_bounds__(256) void qkv_gemm(
    const unsigned short* __restrict__ Xb, const unsigned short* __restrict__ Wt,
    const float* __restrict__ bq, const float* __restrict__ bk, const float* __restrict__ bv,
    unsigned short* __restrict__ Qh, unsigned short* __restrict__ Kh,
    unsigned short* __restrict__ Vh) {
    __shared__ __align__(16) unsigned short lA[2][128 * 32];
    __shared__ __align__(16) unsigned short lB[2][64 * 32];
    const int t = threadIdx.x;
    const int wave = t >> 6, lane = t & 63;
    const int l15 = lane & 15, quad = lane >> 4;
    const int m0 = blockIdx.x * 128;
    const int n0 = blockIdx.y * 64;
    const int wm = wave * 32;

    f32x4 acc[2][4] = {};

    auto stage = [&](int k0, int b) {
        #pragma unroll
        for (int r = 0; r < 2; ++r) {
            int ci = r * 256 + t;
            async16(Xb + (m0 + (ci >> 2)) * HIDD + k0 + (ci & 3) * 8,
                    &lA[b][(r * 256 + wave * 64) * 8]);
        }
        async16(Wt + (n0 + (t >> 2)) * HIDD + k0 + (t & 3) * 8,
                &lB[b][(wave * 64) * 8]);
    };

    stage(0, 0);
    for (int ki = 0; ki < 24; ++ki) {
        const int cur = ki & 1;
        __syncthreads();
        if (ki < 23) stage((ki + 1) * 32, cur ^ 1);
        bf16x8 af[2], bf[4];
        #pragma unroll
        for (int i = 0; i < 2; ++i)
            af[i] = *(const bf16x8*)&lA[cur][(wm + i * 16 + l15) * 32 + quad * 8];
        #pragma unroll
        for (int j = 0; j < 4; ++j)
            bf[j] = *(const bf16x8*)&lB[cur][(j * 16 + l15) * 32 + quad * 8];
        #pragma unroll
        for (int i = 0; i < 2; ++i)
            #pragma unroll
            for (int j = 0; j < 4; ++j)
                acc[i][j] = __builtin_amdgcn_mfma_f32_16x16x32_bf16(af[i], bf[j], acc[i][j], 0, 0, 0);
    }

    const int sect = (n0 >= 1536) ? 2 : (n0 >= 768) ? 1 : 0;
    const float* bias = (sect == 0) ? bq : (sect == 1) ? bk : bv;
    unsigned short* dst = (sect == 0) ? Qh : (sect == 1) ? Kh : Vh;
    const float scale = (sect == 0) ? 0.125f : 1.0f;
    #pragma unroll
    for (int i = 0; i < 2; ++i) {
        #pragma unroll
        for (int j = 0; j < 4; ++j) {
            int n  = n0 + j * 16 + l15;
            int nn = n - sect * HIDD;
            int h = nn >> 6, d = nn & 63;
            float bval = bias[nn];
            #pragma unroll
            for (int r = 0; r < 4; ++r) {
                int m = m0 + wm + i * 16 + quad * 4 + r;
                int b = m >> 10, s = m & 1023;
                float v = (acc[i][j][r] + bval) * scale;
                dst[((size_t)(b * NH + h) * SS + s) * DH + d] = f2b(v);
            }
        }
    }
}

// ------------- kernel 3b: Vh [bh][s][d] -> VhT [bh][d][s] -------------
__global__ __launch_bounds__(256) void transpose_v(
    const unsigned short* __restrict__ Vh, unsigned short* __restrict__ VhT) {
    __shared__ unsigned short tile[64][65];
    const int t = threadIdx.x;
    const int bh = blockIdx.y;
    const int s0 = blockIdx.x * 64;
    const int tx = t & 63, ty = t >> 6;
    const unsigned short* src = Vh + (size_t)bh * SS * DH;
    #pragma unroll
    for (int p = 0; p < 16; ++p)
        tile[ty + p * 4][tx] = src[(size_t)(s0 + ty + p * 4) * DH + tx];
    __syncthreads();
    unsigned short* dst = VhT + (size_t)bh * DH * SS;
    #pragma unroll
    for (int p = 0; p < 16; ++p)
        dst[(size_t)(ty + p * 4) * SS + s0 + tx] = tile[tx][ty + p * 4];
}

// ------------- kernel 4: flash attention, LDS-resident K/V -------------
// grid: (S/32, BH), 128 threads (2 waves), each wave owns 16 q-rows and
// streams ALL 1024 keys (no combine). K/V tiles: global->LDS async,
// double-buffered, block-shared, XOR-swizzled at fetch so frag ds_read_b128
// is conflict-free. Bias: global->LDS async per wave (zero VGPR cost).
// Only persistent VGPRs: Q frags + accumulators -> no spills.
__global__ __launch_bounds__(128) void flash_attn(
    const unsigned short* __restrict__ Qh, const unsigned short* __restrict__ Kh,
    const unsigned short* __restrict__ VhT,
    const float* __restrict__ rel, const float* __restrict__ rel2d,
    const float* __restrict__ amask, const float* __restrict__ hmask,
    float* __restrict__ out) {
    // [0,16384)  lK[2] (2 x 64x64 bf16, swizzled)
    // [16384,32768) lV[2]
    // [32768,49152) bias: wave w at +w*8192 (stgA 4KB | stgB 4KB)
    // [49152,53760) P: wave w at +w*2304 (16x72 bf16)
    __shared__ __align__(16) char smemraw[53760];

    const int t = threadIdx.x;
    const int wave = t >> 6, lane = t & 63;
    const int l15 = lane & 15, quad = lane >> 4;
    const int l7 = l15 & 7;
    const int bh = blockIdx.y;
    const int b = bh / NH, h = bh % NH;
    const int m0w = blockIdx.x * 32 + wave * 16;

    const unsigned short* Qp = Qh + (size_t)bh * SS * DH;
    const unsigned short* Kp = Kh + (size_t)bh * SS * DH;
    const unsigned short* Vp = VhT + (size_t)bh * DH * SS;
    const float* relp  = rel   + (size_t)bh * SS * SS;
    const float* rel2p = rel2d + (size_t)bh * SS * SS;
    const float* maskp = amask + (size_t)b * SS;

    float* stgA = (float*)(smemraw + 32768 + wave * 8192);
    float* stgB = stgA + 1024;
    unsigned short* Pw = (unsigned short*)(smemraw + 49152) + wave * (16 * 72);

    // stage 64x64 K (row=key, swizzled d-chunks) and V^T (row=d, swizzled
    // key-chunks) into buffer buf. 4 async16 each per thread.
    auto stage_kv = [&](int j0, int buf) {
        unsigned short* dK = (unsigned short*)(smemraw + buf * 8192);
        unsigned short* dV = (unsigned short*)(smemraw + 16384 + buf * 8192);
        #pragma unroll
        for (int i = 0; i < 4; ++i) {
            int ci = i * 128 + t;                 // 0..511
            int row = ci >> 3, sc = ci & 7;
            int g = sc ^ (row & 7);               // fetch-side XOR swizzle
            async16(Kp + (size_t)(j0 + row) * DH + g * 8,
                    dK + (i * 128 + wave * 64) * 8);
            async16(Vp + (size_t)row * SS + j0 + g * 8,
                    dV + (i * 128 + wave * 64) * 8);
        }
    };

    // stage this wave's 16x64 bias tiles (row-major fp32)
    auto stage_bias = [&](int j0) {
        #pragma unroll
        for (int i = 0; i < 4; ++i) {
            async16(relp  + (size_t)(m0w + 4 * i + quad) * SS + j0 + l15 * 4,
                    (char*)stgA + i * 1024);
            async16(rel2p + (size_t)(m0w + 4 * i + quad) * SS + j0 + l15 * 4,
                    (char*)stgB + i * 1024);
        }
    };

    bf16x8 qf0 = *(const bf16x8*)&Qp[(m0w + l15) * DH + quad * 8];
    bf16x8 qf1 = *(const bf16x8*)&Qp[(m0w + l15) * DH + 32 + quad * 8];

    f32x4 o[4] = {};
    float mrow[4] = {-1e30f, -1e30f, -1e30f, -1e30f};
    float lrow[4] = {0.f, 0.f, 0.f, 0.f};

    stage_kv(0, 0);
    __syncthreads();   // drains tile-0 staging

    for (int tt = 0; tt < 16; ++tt) {
        const int j0 = tt * 64, cur = tt & 1;
        const unsigned short* cK = (const unsigned short*)(smemraw + cur * 8192);
        const unsigned short* cV = (const unsigned short*)(smemraw + 16384 + cur * 8192);

        // ---- issue: bias (oldest 8) then next K/V (8) ----
        stage_bias(j0);
        if (tt < 15) stage_kv(j0 + 64, cur ^ 1);

        float mk[4];
        #pragma unroll
        for (int c = 0; c < 4; ++c) mk[c] = maskp[j0 + c * 16 + l15];

        // ---- QK^T from LDS buf[cur] (drained by previous barrier) ----
        f32x4 sc4[4] = {};
        #pragma unroll
        for (int c = 0; c < 4; ++c) {
            int row = c * 16 + l15;
            bf16x8 k0f = *(const bf16x8*)&cK[row * 64 + (quad ^ l7) * 8];
            bf16x8 k1f = *(const bf16x8*)&cK[row * 64 + ((quad + 4) ^ l7) * 8];
            sc4[c] = __builtin_amdgcn_mfma_f32_16x16x32_bf16(qf0, k0f, sc4[c], 0, 0, 0);
            sc4[c] = __builtin_amdgcn_mfma_f32_16x16x32_bf16(qf1, k1f, sc4[c], 0, 0, 0);
        }

        // ---- drain bias (first-issued 8 of >=16 outstanding) ----
        if (tt < 15) { asm volatile("s_waitcnt vmcnt(8)" ::: "memory"); }
        else         { asm volatile("s_waitcnt vmcnt(0)" ::: "memory"); }

        // ---- bias add in C layout ----
        float sv[4][4];
        #pragma unroll
        for (int c = 0; c < 4; ++c)
            #pragma unroll
            for (int r = 0; r < 4; ++r) {
                int fi = (quad * 4 + r) * 64 + c * 16 + l15;
                sv[c][r] = sc4[c][r] + (stgA[fi] + stgB[fi]) * 0.125f + mk[c];
            }

        // ---- online softmax per row (reg r <-> row quad*4+r) ----
        float alpha[4];
        #pragma unroll
        for (int r = 0; r < 4; ++r) {
            float mx = fmaxf(fmaxf(sv[0][r], sv[1][r]), fmaxf(sv[2][r], sv[3][r]));
            #pragma unroll
            for (int off = 1; off < 16; off <<= 1) mx = fmaxf(mx, __shfl_xor(mx, off, 64));
            float mnew = fmaxf(mrow[r], mx);
            alpha[r] = __expf(mrow[r] - mnew);
            mrow[r] = mnew;
            float rs = 0.f;
            #pragma unroll
            for (int c = 0; c < 4; ++c) {
                float p = __expf(sv[c][r] - mnew);
                sv[c][r] = p;
                rs += p;
            }
            #pragma unroll
            for (int off = 1; off < 16; off <<= 1) rs += __shfl_xor(rs, off, 64);
            lrow[r] = lrow[r] * alpha[r] + rs;
            o[0][r] *= alpha[r]; o[1][r] *= alpha[r]; o[2][r] *= alpha[r]; o[3][r] *= alpha[r];
        }

        // ---- P -> LDS (A-operand layout) ----
        #pragma unroll
        for (int c = 0; c < 4; ++c)
            #pragma unroll
            for (int r = 0; r < 4; ++r)
                Pw[(quad * 4 + r) * 72 + c * 16 + l15] = f2b(sv[c][r]);

        bf16x8 pf0 = *(const bf16x8*)&Pw[l15 * 72 + quad * 8];
        bf16x8 pf1 = *(const bf16x8*)&Pw[l15 * 72 + 32 + quad * 8];

        // ---- O += P . V from LDS buf[cur] ----
        #pragma unroll
        for (int dt = 0; dt < 4; ++dt) {
            int row = dt * 16 + l15;
            bf16x8 v0f = *(const bf16x8*)&cV[row * 64 + (quad ^ l7) * 8];
            bf16x8 v1f = *(const bf16x8*)&cV[row * 64 + ((quad + 4) ^ l7) * 8];
            o[dt] = __builtin_amdgcn_mfma_f32_16x16x32_bf16(pf0, v0f, o[dt], 0, 0, 0);
            o[dt] = __builtin_amdgcn_mfma_f32_16x16x32_bf16(pf1, v1f, o[dt], 0, 0, 0);
        }

        __syncthreads();   // buf[cur] free for overwrite; drains in-flight KV
    }

    // ---- epilogue: each wave owns its rows, no combine ----
    const float hm = hmask[h];
    #pragma unroll
    for (int r = 0; r < 4; ++r) {
        float inv = hm / lrow[r];
        int s = m0w + quad * 4 + r;
        float* op = out + ((size_t)(b * SS + s)) * HIDD + h * DH;
        #pragma unroll
        for (int dt = 0; dt < 4; ++dt) op[dt * 16 + l15] = o[dt][r] * inv;
    }
}

extern "C" void kernel_launch(void* const* d_in, const int* in_sizes, int n_in,
                              void* d_out, int out_size, void* d_ws, size_t ws_size,
                              hipStream_t stream) {
    const float* hs    = (const float*)d_in[0];
    const float* am    = (const float*)d_in[1];
    const float* hm    = (const float*)d_in[2];
    const float* rel   = (const float*)d_in[3];
    const float* rel2d = (const float*)d_in[4];
    const float* Wq    = (const float*)d_in[5];
    const float* bq    = (const float*)d_in[6];
    const float* Wk    = (const float*)d_in[7];
    const float* bk    = (const float*)d_in[8];
    const float* Wv    = (const float*)d_in[9];
    const float* bv    = (const float*)d_in[10];
    float* out = (float*)d_out;

    unsigned short* Xb  = (unsigned short*)d_ws;              // 2048*768
    unsigned short* Wt  = Xb + 2048 * HIDD;                   // 3*768*768
    unsigned short* Qh  = Wt + 3 * HIDD * HIDD;               // 24*1024*64 each
    unsigned short* Kh  = Qh + (size_t)BH * SS * DH;
    unsigned short* Vh  = Kh + (size_t)BH * SS * DH;
    unsigned short* VhT = Vh + (size_t)BH * SS * DH;

    cvt_x<<<(2048 * HIDD / 4) / 256, 256, 0, stream>>>(hs, Xb);
    dim3 gT(24, 24, 3);
    transpose_w<<<gT, 256, 0, stream>>>(Wq, Wk, Wv, Wt);
    dim3 gG(16, 36);
    qkv_gemm<<<gG, 256, 0, stream>>>(Xb, Wt, bq, bk, bv, Qh, Kh, Vh);
    dim3 gV(16, BH);
    transpose_v<<<gV, 256, 0, stream>>>(Vh, VhT);
    dim3 gF(32, BH);
    flash_attn<<<gF, 128, 0, stream>>>(Qh, Kh, VhT, rel, rel2d, am, hm, out);
}